// Round 21
// baseline (958.112 us; speedup 1.0000x reference)
//
#include <hip/hip_runtime.h>
#include <stdint.h>
#include <math.h>

// Bit-exact replication of img + jax.random.poisson(fold_in(key(0),1), 500, (3,4096,4096)).
// NUMERICS FROZEN (r17, absmax=0.0). Perf r21: chunk-local resolution with dense LDS
// k-staging -> all global IO coalesced exactly once per element (fixes r20's 2.1x
// write amplification). Order-only changes; decisions bit-identical.

#pragma clang fp contract(off)

#define TOTAL_ELEMS 50331648u
#define N_BLOCKS    2048
#define N_TPB       256
#define TOTAL_THREADS 524288u          // N_BLOCKS * N_TPB
#define ELEMS_PER_THREAD 96            // 524288 * 96 = 50331648
#define CAP 32
#define TAB_LO 256
#define TAB_N  512
#define CHUNK_J 4                      // 1024 elements per chunk
#define QCAP2 256                      // per-chunk reject queue (mean 118, +13 sigma)
#define AQ_CAP 384                     // per-chunk accept2 queue (mean 245, +9 sigma)
#define LOG_LAM ((float)6.2146080984221914)   // CR f32(ln 500)

__device__ __forceinline__ uint32_t rotl32(uint32_t v, uint32_t r) {
  return (v << r) | (v >> (32u - r));
}

// Threefry-2x32, 20 rounds, exactly as jax/_src/prng.py
__device__ __forceinline__ void tf2x32(uint32_t k0, uint32_t k1,
                                       uint32_t c0, uint32_t c1,
                                       uint32_t& o0, uint32_t& o1) {
  uint32_t ks2 = k0 ^ k1 ^ 0x1BD11BDAu;
  uint32_t x0 = c0 + k0;
  uint32_t x1 = c1 + k1;
#define TF_R(r) { x0 += x1; x1 = rotl32(x1, r); x1 ^= x0; }
  TF_R(13u) TF_R(15u) TF_R(26u) TF_R(6u)
  x0 += k1;  x1 += ks2 + 1u;
  TF_R(17u) TF_R(29u) TF_R(16u) TF_R(24u)
  x0 += ks2; x1 += k0 + 2u;
  TF_R(13u) TF_R(15u) TF_R(26u) TF_R(6u)
  x0 += k0;  x1 += k1 + 3u;
  TF_R(17u) TF_R(29u) TF_R(16u) TF_R(24u)
  x0 += k1;  x1 += ks2 + 4u;
  TF_R(13u) TF_R(15u) TF_R(26u) TF_R(6u)
  x0 += ks2; x1 += k0 + 5u;
#undef TF_R
  o0 = x0; o1 = x1;
}

// XLA:CPU GenerateVF32Log: Cephes 3-way split, DAG-contracted. (FROZEN)
__device__ __forceinline__ float xla_logf(float xin) {
  #pragma clang fp contract(off)
  if (xin == 0.0f) return -__builtin_inff();
  if (!(xin > 0.0f)) return __builtin_nanf("");
  float x = fmaxf(xin, __uint_as_float(0x00800000u));
  uint32_t ix = __float_as_uint(x);
  float e = 1.0f + (float)((int32_t)(ix >> 23) - 127);
  x = __uint_as_float((ix & 0x807fffffu) | 0x3f000000u);
  const float SQRTHF = (float)0.707106781186547524;
  bool m = x < SQRTHF;
  float tmp1 = m ? x : 0.0f;
  x = x - 1.0f;
  e = e - (m ? 1.0f : 0.0f);
  x = x + tmp1;
  float x2 = x * x;
  float x3 = x2 * x;
  float y  = __builtin_fmaf(x, (float)7.0376836292e-2,  (float)-1.1514610310e-1);
  float y1 = __builtin_fmaf(x, (float)-1.2420140846e-1, (float)1.4249322787e-1);
  float y2 = __builtin_fmaf(x, (float)2.0000714765e-1,  (float)-2.4999993993e-1);
  y  = __builtin_fmaf(y,  x, (float)1.1676998740e-1);
  y1 = __builtin_fmaf(y1, x, (float)-1.6668057665e-1);
  y2 = __builtin_fmaf(y2, x, (float)3.3333331174e-1);
  y  = __builtin_fmaf(y, x3, y1);
  y  = __builtin_fmaf(y, x3, y2);
  float yq1 = (float)-2.12194440e-4 * e;
  y = __builtin_fmaf(y, x3, yq1);
  x = __builtin_fmaf(-0.5f, x2, x);
  x = x + y;
  x = __builtin_fmaf((float)0.693359375, e, x);
  return x;
}

// XLA EmitLog1p (f32). (FROZEN)
__device__ __forceinline__ float xla_log1pf(float x) {
  #pragma clang fp contract(off)
  float for_small = __builtin_fmaf(-0.5f, x, 1.0f) * x;
  float for_large = xla_logf(x + 1.0f);
  return (fabsf(x) < (float)1e-4) ? for_small : for_large;
}

// CHLO/XLA Lgamma with z*(1/7.5) recip-mul. (FROZEN)
__device__ __forceinline__ float xla_lgammaf(float a) {
  #pragma clang fp contract(off)
  float z = a - 1.0f;
  float sum = (float)0.99999999999980993227684700473478;
  sum = sum + (float)676.520368121885098567009190444019   / (z + 1.0f);
  sum = sum + (float)-1259.13921672240287047156078755283  / (z + 2.0f);
  sum = sum + (float)771.3234287776530788486528258894     / (z + 3.0f);
  sum = sum + (float)-176.61502916214059906584551354      / (z + 4.0f);
  sum = sum + (float)12.507343278686904814458936853       / (z + 5.0f);
  sum = sum + (float)-0.13857109526572011689554707        / (z + 6.0f);
  sum = sum + (float)9.984369578019570859563e-6           / (z + 7.0f);
  sum = sum + (float)1.50563273514931155834e-7            / (z + 8.0f);
  float t = (float)7.5 + z;
  float w = z * (float)(1.0 / 7.5);
  float log_t = (float)2.0149030205422647 + xla_log1pf(w);
  float factor = (z + 0.5f) - t / log_t;
  float log_y = __builtin_fmaf(factor, log_t, (float)0.91893853320467274178)
                + xla_logf(sum);
  return log_y;
}

__device__ __forceinline__ float t_of_k(float k) {
  #pragma clang fp contract(off)
  return __builtin_fmaf(k, LOG_LAM, -500.0f) - xla_lgammaf(k + 1.0f);
}

struct PC { float bb, aa, twoa, inv_alpha, v_r; };

__device__ __forceinline__ PC make_pc() {
  #pragma clang fp contract(off)
  PC c;
  float sq = (float)22.360679774997896;            // f32(sqrt(500)), CR
  c.bb = (float)0.931 + (float)2.53 * sq;
  c.aa = (float)-0.059 + (float)0.02483 * c.bb;
  c.twoa = 2.0f * c.aa;
  c.inv_alpha = (float)1.1239 + (float)1.1328 / (c.bb - (float)3.4);
  c.v_r = (float)0.9277 - (float)3.6224 / (c.bb - 2.0f);
  return c;
}

__device__ __forceinline__ float bits_to_u01(uint32_t bits) {
  return __uint_as_float((bits >> 9) | 0x3f800000u) - 1.0f;
}

__device__ __forceinline__ float t_lookup(float k, const float* __restrict__ ttab) {
  int ki = (int)k;
  if (ki >= TAB_LO && ki < TAB_LO + TAB_N) return ttab[ki - TAB_LO];
  return t_of_k(k);
}

// Full Hormann trial. Decision-identical to r17.
__device__ __forceinline__ bool hormann_accept(uint32_t ubits, uint32_t vbits,
                                               const PC& c, const float* __restrict__ ttab,
                                               float& kout) {
  #pragma clang fp contract(off)
  float u01 = bits_to_u01(ubits);
  float v   = bits_to_u01(vbits);
  float u = u01 - 0.5f;
  float us = 0.5f - fabsf(u);
  float inner = c.twoa / us + c.bb;
  float kq = __builtin_fmaf(inner, u, 500.43f);
  float k = floorf(kq);
  kout = k;
  bool accept1 = (us >= (float)0.07) & (v <= c.v_r);
  if (accept1) return true;
  bool reject = (k < 0.0f) | ((us < (float)0.013) & (v > us));
  if (reject) return false;
  float s = xla_logf((v * c.inv_alpha) / (c.aa / (us * us) + c.bb));
  return s <= t_lookup(k, ttab);
}

__device__ __forceinline__ uint32_t pbits(uint32_t s0, uint32_t s1, uint32_t e) {
  uint32_t a, b;
  tf2x32(s0, s1, 0u, e, a, b);
  return a ^ b;
}

__device__ __forceinline__ bool trial(uint32_t e, uint32_t tlvl,
                                      const uint32_t (&ssub)[CAP][4],
                                      const PC& c, const float* __restrict__ ttab,
                                      float& kout) {
  uint32_t ub = pbits(ssub[tlvl][0], ssub[tlvl][1], e);
  uint32_t vb = pbits(ssub[tlvl][2], ssub[tlvl][3], e);
  return hormann_accept(ub, vb, c, ttab, kout);
}

__device__ __forceinline__ uint32_t lane_id() {
  return __builtin_amdgcn_mbcnt_hi(~0u, __builtin_amdgcn_mbcnt_lo(~0u, 0u));
}

// Wave-aggregated queue push: one atomicAdd per wave.
__device__ __forceinline__ uint32_t wq_push(uint32_t* counter, bool push) {
  uint64_t mask = __ballot(push);
  if (mask == 0ull) return 0xFFFFFFFFu;
  uint32_t lane = lane_id();
  int leader = (int)(__ffsll((unsigned long long)mask) - 1);
  uint32_t base = 0;
  if ((int)lane == leader) base = atomicAdd(counter, (uint32_t)__popcll(mask));
  base = (uint32_t)__shfl((int)base, leader);
  uint32_t off = (uint32_t)__popcll(mask & ((1ull << lane) - 1ull));
  return base + off;
}

// Build subkey chain (thread 0) and t(k)-table; syncs at end.
__device__ __forceinline__ void build_shared(uint32_t n, uint32_t (&ssub)[CAP][4],
                                             float* ttab) {
  for (uint32_t i = threadIdx.x; i < TAB_N; i += N_TPB) {
    ttab[i] = t_of_k((float)(int)(TAB_LO + (int)i));
  }
  if (threadIdx.x == 0) {
    uint32_t k0, k1;
    tf2x32(0u, 0u, 0u, 1u, k0, k1);   // noise_key = fold_in(key(0), 1)
    for (uint32_t t = 0; t < n; ++t) {
      uint32_t nk0, nk1, s00, s01, s10, s11;
      tf2x32(k0, k1, 0u, 0u, nk0, nk1);
      tf2x32(k0, k1, 0u, 1u, s00, s01);
      tf2x32(k0, k1, 0u, 2u, s10, s11);
      ssub[t][0] = s00; ssub[t][1] = s01;
      ssub[t][2] = s10; ssub[t][3] = s11;
      k0 = nk0; k1 = nk1;
    }
  }
  __syncthreads();
}

__global__ void pn_init(uint32_t* nmax) { *nmax = 0u; }

// ---------------- Pass 1: N = 1 + max first-accept level (chunk-local) ----------------
__global__ __launch_bounds__(N_TPB) void pn_pass1(uint32_t* nmax) {
  __shared__ uint32_t ssub[CAP][4];
  __shared__ float ttab[TAB_N];
  __shared__ uint16_t qf[2][QCAP2];
  __shared__ uint32_t qn[2];
  __shared__ uint32_t shN;
  __shared__ uint16_t aq_li[AQ_CAP];
  __shared__ float aq_u[AQ_CAP];
  __shared__ float aq_v[AQ_CAP];
  __shared__ uint32_t aqn;
  if (threadIdx.x == 0) shN = 1;
  build_shared(CAP, ssub, ttab);
  PC c = make_pc();
  uint32_t blockBase = blockIdx.x * N_TPB;
  uint32_t localN = 1;
  for (int jc = 0; jc < ELEMS_PER_THREAD; jc += CHUNK_J) {
    if (threadIdx.x == 0) { aqn = 0; qn[0] = 0; qn[1] = 0; }
    __syncthreads();
    // Phase A: level 0, accept1-only test; defer the rest.
    for (int j = jc; j < jc + CHUNK_J; ++j) {
      uint32_t e = blockBase + threadIdx.x + (uint32_t)j * TOTAL_THREADS;
      uint16_t li = (uint16_t)(((uint32_t)j << 8) | threadIdx.x);
      uint32_t ub = pbits(ssub[0][0], ssub[0][1], e);
      uint32_t vb = pbits(ssub[0][2], ssub[0][3], e);
      float u01 = bits_to_u01(ub);
      float v   = bits_to_u01(vb);
      float u = u01 - 0.5f;
      float us = 0.5f - fabsf(u);
      bool accept1 = (us >= (float)0.07) & (v <= c.v_r);
      bool pend = !accept1;
      uint32_t ai = wq_push(&aqn, pend);
      if (pend) {
        if (__builtin_expect(ai < AQ_CAP, 1)) {
          aq_li[ai] = li; aq_u[ai] = u; aq_v[ai] = v;
        } else {
          float inner = c.twoa / us + c.bb;
          float k = floorf(__builtin_fmaf(inner, u, 500.43f));
          bool reject = (k < 0.0f) | ((us < (float)0.013) & (v > us));
          bool acc = false;
          if (!reject) {
            float s = xla_logf((v * c.inv_alpha) / (c.aa / (us * us) + c.bb));
            acc = (s <= t_lookup(k, ttab));
          }
          if (!acc) {
            uint32_t qi = atomicAdd(&qn[0], 1u);
            if (qi < QCAP2) qf[0][qi] = li;
            else {
              float kk; uint32_t Lc = CAP;
              for (uint32_t t2 = 1; t2 < CAP; ++t2)
                if (trial(e, t2, ssub, c, ttab, kk)) { Lc = t2 + 1u; break; }
              atomicMax(&shN, Lc);
            }
          }
        }
      }
    }
    __syncthreads();
    // Dense flush of deferred level-0 work.
    uint32_t an = aqn; if (an > AQ_CAP) an = AQ_CAP;
    for (uint32_t i = threadIdx.x; i < an; i += N_TPB) {
      uint16_t li = aq_li[i];
      float u = aq_u[i], v = aq_v[i];
      float us = 0.5f - fabsf(u);
      float inner = c.twoa / us + c.bb;
      float k = floorf(__builtin_fmaf(inner, u, 500.43f));
      bool reject = (k < 0.0f) | ((us < (float)0.013) & (v > us));
      bool acc = false;
      if (!reject) {
        float s = xla_logf((v * c.inv_alpha) / (c.aa / (us * us) + c.bb));
        acc = (s <= t_lookup(k, ttab));
      }
      bool fail = !acc;
      uint32_t qi = wq_push(&qn[0], fail);
      if (fail) {
        if (__builtin_expect(qi < QCAP2, 1)) qf[0][qi] = li;
        else {
          uint32_t e = blockBase + (li & 255u) + (uint32_t)(li >> 8) * TOTAL_THREADS;
          float kk; uint32_t Lc = CAP;
          for (uint32_t t2 = 1; t2 < CAP; ++t2)
            if (trial(e, t2, ssub, c, ttab, kk)) { Lc = t2 + 1u; break; }
          atomicMax(&shN, Lc);
        }
      }
    }
    __syncthreads();
    // Chunk-local level phases.
    int cur = 0;
    for (uint32_t t = 1; t < CAP; ++t) {
      uint32_t n = qn[cur]; if (n > QCAP2) n = QCAP2;
      if (n == 0) break;
      if (localN < t + 1u) localN = t + 1u;
      if (threadIdx.x == 0) qn[cur ^ 1] = 0;
      __syncthreads();
      for (uint32_t i = threadIdx.x; i < n; i += N_TPB) {
        uint16_t li = qf[cur][i];
        uint32_t e = blockBase + (li & 255u) + (uint32_t)(li >> 8) * TOTAL_THREADS;
        float kk;
        bool fail = !trial(e, t, ssub, c, ttab, kk);
        uint32_t qi = wq_push(&qn[cur ^ 1], fail);
        if (fail) {
          if (__builtin_expect(qi < QCAP2, 1)) qf[cur ^ 1][qi] = li;
          else {
            uint32_t Lc = CAP;
            for (uint32_t t2 = t + 1; t2 < CAP; ++t2)
              if (trial(e, t2, ssub, c, ttab, kk)) { Lc = t2 + 1u; break; }
            atomicMax(&shN, Lc);
          }
        }
      }
      __syncthreads();
      cur ^= 1;
    }
    __syncthreads();
  }
  if (threadIdx.x == 0) {
    uint32_t m = shN; if (localN > m) m = localN;
    atomicMax(nmax, m);
  }
}

// ---------------- Pass 2: last-accept, chunk-local with dense k-staging ----------------
__global__ __launch_bounds__(N_TPB) void pn_pass2(const float* __restrict__ img,
                                                  float* __restrict__ out,
                                                  const uint32_t* __restrict__ nptr) {
  __shared__ uint32_t ssub[CAP][4];
  __shared__ float ttab[TAB_N];
  __shared__ uint16_t qf[2][QCAP2];
  __shared__ uint32_t qn[2];
  __shared__ uint16_t aq_li[AQ_CAP];
  __shared__ float aq_k[AQ_CAP];
  __shared__ float aq_us[AQ_CAP];
  __shared__ float aq_v[AQ_CAP];
  __shared__ uint32_t aqn;
  __shared__ float karr[N_TPB * CHUNK_J];   // dense per-chunk k results
  uint32_t N = *nptr;
  if (N < 1u) N = 1u;
  if (N > CAP) N = CAP;
  build_shared(N, ssub, ttab);
  PC c = make_pc();
  uint32_t blockBase = blockIdx.x * N_TPB;
  uint32_t top = N - 1u;
  for (int jc = 0; jc < ELEMS_PER_THREAD; jc += CHUNK_J) {
    if (threadIdx.x == 0) { aqn = 0; qn[0] = 0; qn[1] = 0; }
    __syncthreads();
    // Phase A: level top for the chunk. karr <- k (accept1) or -1; defer accept2.
    for (int j = jc; j < jc + CHUNK_J; ++j) {
      int lj = j - jc;
      uint32_t e = blockBase + threadIdx.x + (uint32_t)j * TOTAL_THREADS;
      uint16_t li = (uint16_t)(((uint32_t)j << 8) | threadIdx.x);
      uint32_t ci = (uint32_t)lj * N_TPB + threadIdx.x;   // chunk-local dense index
      uint32_t ub = pbits(ssub[top][0], ssub[top][1], e);
      uint32_t vb = pbits(ssub[top][2], ssub[top][3], e);
      float u01 = bits_to_u01(ub);
      float v   = bits_to_u01(vb);
      float u = u01 - 0.5f;
      float us = 0.5f - fabsf(u);
      float inner = c.twoa / us + c.bb;
      float k = floorf(__builtin_fmaf(inner, u, 500.43f));
      bool accept1 = (us >= (float)0.07) & (v <= c.v_r);
      bool reject  = (!accept1) & ((k < 0.0f) | ((us < (float)0.013) & (v > us)));
      bool need2   = (!accept1) & (!reject);
      karr[ci] = accept1 ? k : -1.0f;
      uint32_t qi = wq_push(&qn[0], reject);
      if (reject) {
        if (__builtin_expect(qi < QCAP2, 1)) qf[0][qi] = li;
        else {
          float kk, kf = -1.0f;
          for (int t2 = (int)top - 1; t2 >= 0; --t2)
            if (trial(e, (uint32_t)t2, ssub, c, ttab, kk)) { kf = kk; break; }
          karr[ci] = kf;
        }
      }
      uint32_t ai = wq_push(&aqn, need2);
      if (need2) {
        if (__builtin_expect(ai < AQ_CAP, 1)) {
          aq_li[ai] = li; aq_k[ai] = k; aq_us[ai] = us; aq_v[ai] = v;
        } else {
          float s = xla_logf((v * c.inv_alpha) / (c.aa / (us * us) + c.bb));
          if (s <= t_lookup(k, ttab)) karr[ci] = k;
          else {
            uint32_t qi2 = atomicAdd(&qn[0], 1u);
            if (qi2 < QCAP2) qf[0][qi2] = li;
            else {
              float kk, kf = -1.0f;
              for (int t2 = (int)top - 1; t2 >= 0; --t2)
                if (trial(e, (uint32_t)t2, ssub, c, ttab, kk)) { kf = kk; break; }
              karr[ci] = kf;
            }
          }
        }
      }
    }
    __syncthreads();
    // Dense accept2 flush for level top.
    uint32_t an = aqn; if (an > AQ_CAP) an = AQ_CAP;
    for (uint32_t i = threadIdx.x; i < an; i += N_TPB) {
      uint16_t li = aq_li[i];
      float k = aq_k[i], us = aq_us[i], v = aq_v[i];
      uint32_t ci = ((uint32_t)(li >> 8) - (uint32_t)jc) * N_TPB + (li & 255u);
      float s = xla_logf((v * c.inv_alpha) / (c.aa / (us * us) + c.bb));
      bool acc = (s <= t_lookup(k, ttab));
      if (acc) karr[ci] = k;
      uint32_t qi = wq_push(&qn[0], !acc);
      if (!acc) {
        if (__builtin_expect(qi < QCAP2, 1)) qf[0][qi] = li;
        else {
          uint32_t e = blockBase + (li & 255u) + (uint32_t)(li >> 8) * TOTAL_THREADS;
          float kk, kf = -1.0f;
          for (int t2 = (int)top - 1; t2 >= 0; --t2)
            if (trial(e, (uint32_t)t2, ssub, c, ttab, kk)) { kf = kk; break; }
          karr[ci] = kf;
        }
      }
    }
    __syncthreads();
    // Chunk-local level phases: top-1 .. 0.
    int cur = 0;
    for (int t = (int)top - 1; t >= 0; --t) {
      uint32_t n = qn[cur]; if (n > QCAP2) n = QCAP2;
      if (n == 0) break;
      if (threadIdx.x == 0) qn[cur ^ 1] = 0;
      __syncthreads();
      for (uint32_t i = threadIdx.x; i < n; i += N_TPB) {
        uint16_t li = qf[cur][i];
        uint32_t e = blockBase + (li & 255u) + (uint32_t)(li >> 8) * TOTAL_THREADS;
        uint32_t ci = ((uint32_t)(li >> 8) - (uint32_t)jc) * N_TPB + (li & 255u);
        float kk;
        bool acc = trial(e, (uint32_t)t, ssub, c, ttab, kk);
        if (acc) karr[ci] = kk;
        uint32_t qi = wq_push(&qn[cur ^ 1], !acc);
        if (!acc) {
          if (__builtin_expect(qi < QCAP2, 1)) qf[cur ^ 1][qi] = li;
          else {
            float kk2, kf = -1.0f;
            for (int t2 = t - 1; t2 >= 0; --t2)
              if (trial(e, (uint32_t)t2, ssub, c, ttab, kk2)) { kf = kk2; break; }
            karr[ci] = kf;
          }
        }
      }
      __syncthreads();
      cur ^= 1;
    }
    __syncthreads();
    // Coalesced IO sweep: exactly one read + one write per element.
    for (int j = jc; j < jc + CHUNK_J; ++j) {
      int lj = j - jc;
      uint32_t e = blockBase + threadIdx.x + (uint32_t)j * TOTAL_THREADS;
      uint32_t ci = (uint32_t)lj * N_TPB + threadIdx.x;
      out[e] = img[e] + karr[ci];
    }
    __syncthreads();
  }
}

extern "C" void kernel_launch(void* const* d_in, const int* in_sizes, int n_in,
                              void* d_out, int out_size, void* d_ws, size_t ws_size,
                              hipStream_t stream) {
  (void)in_sizes; (void)n_in; (void)out_size; (void)ws_size;
  const float* img = (const float*)d_in[0];
  float* out = (float*)d_out;
  uint32_t* nmax = (uint32_t*)d_ws;
  pn_init<<<1, 1, 0, stream>>>(nmax);
  pn_pass1<<<N_BLOCKS, N_TPB, 0, stream>>>(nmax);
  pn_pass2<<<N_BLOCKS, N_TPB, 0, stream>>>(img, out, nmax);
}

// Round 22
// 755.195 us; speedup vs baseline: 1.2687x; 1.2687x over previous
//
#include <hip/hip_runtime.h>
#include <stdint.h>
#include <math.h>

// Bit-exact replication of img + jax.random.poisson(fold_in(key(0),1), 500, (3,4096,4096)).
// NUMERICS FROZEN (r17, absmax=0.0). Perf r22: r19 block-queue structure +
// (1) barrier-free wave-local accept2 deferral, (2) 2-element ILP batching in
// phase A, (3) LDS diet -> 7 blocks/CU. Order-only changes; decisions bit-identical.

#pragma clang fp contract(off)

#define TOTAL_ELEMS 50331648u
#define N_BLOCKS    2048
#define N_TPB       256
#define TOTAL_THREADS 524288u          // N_BLOCKS * N_TPB
#define ELEMS_PER_THREAD 96            // 524288 * 96 = 50331648
#define CAP 32
#define TAB_LO 320
#define TAB_N  384                     // covers live k range [370,631]
#define QCAP 3072                      // block reject queue (mean 2826 + 4.9 sigma)
#define CHUNK_J 8                      // wave-local flush interval
#define WAQ_CAP 176                    // per-wave defer cap (mean 132 + 4.4 sigma)
#define NWAVES 4
#define LOG_LAM ((float)6.2146080984221914)   // CR f32(ln 500)

__device__ __forceinline__ uint32_t rotl32(uint32_t v, uint32_t r) {
  return (v << r) | (v >> (32u - r));
}

// Threefry-2x32, 20 rounds, exactly as jax/_src/prng.py
__device__ __forceinline__ void tf2x32(uint32_t k0, uint32_t k1,
                                       uint32_t c0, uint32_t c1,
                                       uint32_t& o0, uint32_t& o1) {
  uint32_t ks2 = k0 ^ k1 ^ 0x1BD11BDAu;
  uint32_t x0 = c0 + k0;
  uint32_t x1 = c1 + k1;
#define TF_R(r) { x0 += x1; x1 = rotl32(x1, r); x1 ^= x0; }
  TF_R(13u) TF_R(15u) TF_R(26u) TF_R(6u)
  x0 += k1;  x1 += ks2 + 1u;
  TF_R(17u) TF_R(29u) TF_R(16u) TF_R(24u)
  x0 += ks2; x1 += k0 + 2u;
  TF_R(13u) TF_R(15u) TF_R(26u) TF_R(6u)
  x0 += k0;  x1 += k1 + 3u;
  TF_R(17u) TF_R(29u) TF_R(16u) TF_R(24u)
  x0 += k1;  x1 += ks2 + 4u;
  TF_R(13u) TF_R(15u) TF_R(26u) TF_R(6u)
  x0 += ks2; x1 += k0 + 5u;
#undef TF_R
  o0 = x0; o1 = x1;
}

// XLA:CPU GenerateVF32Log: Cephes 3-way split, DAG-contracted. (FROZEN)
__device__ __forceinline__ float xla_logf(float xin) {
  #pragma clang fp contract(off)
  if (xin == 0.0f) return -__builtin_inff();
  if (!(xin > 0.0f)) return __builtin_nanf("");
  float x = fmaxf(xin, __uint_as_float(0x00800000u));
  uint32_t ix = __float_as_uint(x);
  float e = 1.0f + (float)((int32_t)(ix >> 23) - 127);
  x = __uint_as_float((ix & 0x807fffffu) | 0x3f000000u);
  const float SQRTHF = (float)0.707106781186547524;
  bool m = x < SQRTHF;
  float tmp1 = m ? x : 0.0f;
  x = x - 1.0f;
  e = e - (m ? 1.0f : 0.0f);
  x = x + tmp1;
  float x2 = x * x;
  float x3 = x2 * x;
  float y  = __builtin_fmaf(x, (float)7.0376836292e-2,  (float)-1.1514610310e-1);
  float y1 = __builtin_fmaf(x, (float)-1.2420140846e-1, (float)1.4249322787e-1);
  float y2 = __builtin_fmaf(x, (float)2.0000714765e-1,  (float)-2.4999993993e-1);
  y  = __builtin_fmaf(y,  x, (float)1.1676998740e-1);
  y1 = __builtin_fmaf(y1, x, (float)-1.6668057665e-1);
  y2 = __builtin_fmaf(y2, x, (float)3.3333331174e-1);
  y  = __builtin_fmaf(y, x3, y1);
  y  = __builtin_fmaf(y, x3, y2);
  float yq1 = (float)-2.12194440e-4 * e;
  y = __builtin_fmaf(y, x3, yq1);
  x = __builtin_fmaf(-0.5f, x2, x);
  x = x + y;
  x = __builtin_fmaf((float)0.693359375, e, x);
  return x;
}

// XLA EmitLog1p (f32). (FROZEN)
__device__ __forceinline__ float xla_log1pf(float x) {
  #pragma clang fp contract(off)
  float for_small = __builtin_fmaf(-0.5f, x, 1.0f) * x;
  float for_large = xla_logf(x + 1.0f);
  return (fabsf(x) < (float)1e-4) ? for_small : for_large;
}

// CHLO/XLA Lgamma with z*(1/7.5) recip-mul. (FROZEN)
__device__ __forceinline__ float xla_lgammaf(float a) {
  #pragma clang fp contract(off)
  float z = a - 1.0f;
  float sum = (float)0.99999999999980993227684700473478;
  sum = sum + (float)676.520368121885098567009190444019   / (z + 1.0f);
  sum = sum + (float)-1259.13921672240287047156078755283  / (z + 2.0f);
  sum = sum + (float)771.3234287776530788486528258894     / (z + 3.0f);
  sum = sum + (float)-176.61502916214059906584551354      / (z + 4.0f);
  sum = sum + (float)12.507343278686904814458936853       / (z + 5.0f);
  sum = sum + (float)-0.13857109526572011689554707        / (z + 6.0f);
  sum = sum + (float)9.984369578019570859563e-6           / (z + 7.0f);
  sum = sum + (float)1.50563273514931155834e-7            / (z + 8.0f);
  float t = (float)7.5 + z;
  float w = z * (float)(1.0 / 7.5);
  float log_t = (float)2.0149030205422647 + xla_log1pf(w);
  float factor = (z + 0.5f) - t / log_t;
  float log_y = __builtin_fmaf(factor, log_t, (float)0.91893853320467274178)
                + xla_logf(sum);
  return log_y;
}

__device__ __forceinline__ float t_of_k(float k) {
  #pragma clang fp contract(off)
  return __builtin_fmaf(k, LOG_LAM, -500.0f) - xla_lgammaf(k + 1.0f);
}

struct PC { float bb, aa, twoa, inv_alpha, v_r; };

__device__ __forceinline__ PC make_pc() {
  #pragma clang fp contract(off)
  PC c;
  float sq = (float)22.360679774997896;            // f32(sqrt(500)), CR
  c.bb = (float)0.931 + (float)2.53 * sq;
  c.aa = (float)-0.059 + (float)0.02483 * c.bb;
  c.twoa = 2.0f * c.aa;
  c.inv_alpha = (float)1.1239 + (float)1.1328 / (c.bb - (float)3.4);
  c.v_r = (float)0.9277 - (float)3.6224 / (c.bb - 2.0f);
  return c;
}

__device__ __forceinline__ float bits_to_u01(uint32_t bits) {
  return __uint_as_float((bits >> 9) | 0x3f800000u) - 1.0f;
}

__device__ __forceinline__ float t_lookup(float k, const float* __restrict__ ttab) {
  int ki = (int)k;
  if (ki >= TAB_LO && ki < TAB_LO + TAB_N) return ttab[ki - TAB_LO];
  return t_of_k(k);
}

// Full Hormann trial (level phases / fallbacks). Decision-identical to r17.
__device__ __forceinline__ bool hormann_accept(uint32_t ubits, uint32_t vbits,
                                               const PC& c, const float* __restrict__ ttab,
                                               float& kout) {
  #pragma clang fp contract(off)
  float u01 = bits_to_u01(ubits);
  float v   = bits_to_u01(vbits);
  float u = u01 - 0.5f;
  float us = 0.5f - fabsf(u);
  float inner = c.twoa / us + c.bb;
  float kq = __builtin_fmaf(inner, u, 500.43f);
  float k = floorf(kq);
  kout = k;
  bool accept1 = (us >= (float)0.07) & (v <= c.v_r);
  if (accept1) return true;
  bool reject = (k < 0.0f) | ((us < (float)0.013) & (v > us));
  if (reject) return false;
  float s = xla_logf((v * c.inv_alpha) / (c.aa / (us * us) + c.bb));
  return s <= t_lookup(k, ttab);
}

__device__ __forceinline__ uint32_t pbits(uint32_t s0, uint32_t s1, uint32_t e) {
  uint32_t a, b;
  tf2x32(s0, s1, 0u, e, a, b);
  return a ^ b;
}

__device__ __forceinline__ bool trial(uint32_t e, uint32_t tlvl,
                                      const uint32_t (&ssub)[CAP][4],
                                      const PC& c, const float* __restrict__ ttab,
                                      float& kout) {
  uint32_t ub = pbits(ssub[tlvl][0], ssub[tlvl][1], e);
  uint32_t vb = pbits(ssub[tlvl][2], ssub[tlvl][3], e);
  return hormann_accept(ub, vb, c, ttab, kout);
}

__device__ __forceinline__ uint32_t lane_id() {
  return __builtin_amdgcn_mbcnt_hi(~0u, __builtin_amdgcn_mbcnt_lo(~0u, 0u));
}

// Wave-aggregated block-queue push (cross-wave, one atomic per wave).
__device__ __forceinline__ uint32_t wq_push(uint32_t* counter, bool push) {
  uint64_t mask = __ballot(push);
  if (mask == 0ull) return 0xFFFFFFFFu;
  uint32_t lane = lane_id();
  int leader = (int)(__ffsll((unsigned long long)mask) - 1);
  uint32_t base = 0;
  if ((int)lane == leader) base = atomicAdd(counter, (uint32_t)__popcll(mask));
  base = (uint32_t)__shfl((int)base, leader);
  uint32_t off = (uint32_t)__popcll(mask & ((1ull << lane) - 1ull));
  return base + off;
}

// Wave-local push: uniform register counter, no atomic, no barrier.
// Returns slot for this lane (valid only if push).
__device__ __forceinline__ uint32_t wl_push(uint32_t& cnt, bool push) {
  uint64_t mask = __ballot(push);
  uint32_t lane = lane_id();
  uint32_t off = cnt + (uint32_t)__popcll(mask & ((1ull << lane) - 1ull));
  cnt += (uint32_t)__popcll(mask);
  return off;
}

// Build subkey chain (thread 0) and t(k)-table; syncs at end.
__device__ __forceinline__ void build_shared(uint32_t n, uint32_t (&ssub)[CAP][4],
                                             float* ttab) {
  for (uint32_t i = threadIdx.x; i < TAB_N; i += N_TPB) {
    ttab[i] = t_of_k((float)(int)(TAB_LO + (int)i));
  }
  if (threadIdx.x == 0) {
    uint32_t k0, k1;
    tf2x32(0u, 0u, 0u, 1u, k0, k1);   // noise_key = fold_in(key(0), 1)
    for (uint32_t t = 0; t < n; ++t) {
      uint32_t nk0, nk1, s00, s01, s10, s11;
      tf2x32(k0, k1, 0u, 0u, nk0, nk1);
      tf2x32(k0, k1, 0u, 1u, s00, s01);
      tf2x32(k0, k1, 0u, 2u, s10, s11);
      ssub[t][0] = s00; ssub[t][1] = s01;
      ssub[t][2] = s10; ssub[t][3] = s11;
      k0 = nk0; k1 = nk1;
    }
  }
  __syncthreads();
}

__global__ void pn_init(uint32_t* nmax) { *nmax = 0u; }

// ---------------- Pass 1: N = 1 + max first-accept level ----------------
__global__ __launch_bounds__(N_TPB) void pn_pass1(uint32_t* nmax) {
  __shared__ uint32_t ssub[CAP][4];
  __shared__ float ttab[TAB_N];
  __shared__ uint16_t qf[2][QCAP];
  __shared__ uint32_t qn[2];
  __shared__ uint32_t shN;
  __shared__ uint16_t wli[NWAVES][WAQ_CAP];
  __shared__ float wu[NWAVES][WAQ_CAP];
  __shared__ float wv[NWAVES][WAQ_CAP];
  if (threadIdx.x == 0) { qn[0] = 0; qn[1] = 0; shN = 1; }
  build_shared(CAP, ssub, ttab);
  PC c = make_pc();
  uint32_t blockBase = blockIdx.x * N_TPB;
  uint32_t wid = threadIdx.x >> 6;
  uint32_t wcnt = 0;
  // Phase A: level 0, accept1 test only; defer the rest wave-locally (no barriers).
  for (int jc = 0; jc < ELEMS_PER_THREAD; jc += CHUNK_J) {
    for (int j = jc; j < jc + CHUNK_J; j += 2) {
      uint32_t eA = blockBase + threadIdx.x + (uint32_t)j * TOTAL_THREADS;
      uint32_t eB = eA + TOTAL_THREADS;
      uint16_t liA = (uint16_t)(((uint32_t)j << 8) | threadIdx.x);
      uint16_t liB = (uint16_t)liA + (uint16_t)256;
      uint32_t ubA = pbits(ssub[0][0], ssub[0][1], eA);
      uint32_t vbA = pbits(ssub[0][2], ssub[0][3], eA);
      uint32_t ubB = pbits(ssub[0][0], ssub[0][1], eB);
      uint32_t vbB = pbits(ssub[0][2], ssub[0][3], eB);
      float uA = bits_to_u01(ubA) - 0.5f, vA = bits_to_u01(vbA);
      float uB = bits_to_u01(ubB) - 0.5f, vB = bits_to_u01(vbB);
      float usA = 0.5f - fabsf(uA), usB = 0.5f - fabsf(uB);
      bool pendA = !((usA >= (float)0.07) & (vA <= c.v_r));
      bool pendB = !((usB >= (float)0.07) & (vB <= c.v_r));
      uint32_t oA = wl_push(wcnt, pendA);
      if (pendA) {
        if (__builtin_expect(oA < WAQ_CAP, 1)) { wli[wid][oA]=liA; wu[wid][oA]=uA; wv[wid][oA]=vA; }
        else {  // rare: resolve level 0 inline
          float inner = c.twoa / usA + c.bb;
          float k = floorf(__builtin_fmaf(inner, uA, 500.43f));
          bool rej = (k < 0.0f) | ((usA < (float)0.013) & (vA > usA));
          bool acc = false;
          if (!rej) {
            float s = xla_logf((vA * c.inv_alpha) / (c.aa / (usA * usA) + c.bb));
            acc = (s <= t_lookup(k, ttab));
          }
          if (!acc) {
            uint32_t qi = atomicAdd(&qn[0], 1u);
            if (qi < QCAP) qf[0][qi] = liA;
            else { float kk; uint32_t Lc = CAP;
              for (uint32_t t2 = 1; t2 < CAP; ++t2)
                if (trial(eA, t2, ssub, c, ttab, kk)) { Lc = t2 + 1u; break; }
              atomicMax(&shN, Lc); }
          }
        }
      }
      uint32_t oB = wl_push(wcnt, pendB);
      if (pendB) {
        if (__builtin_expect(oB < WAQ_CAP, 1)) { wli[wid][oB]=liB; wu[wid][oB]=uB; wv[wid][oB]=vB; }
        else {
          float inner = c.twoa / usB + c.bb;
          float k = floorf(__builtin_fmaf(inner, uB, 500.43f));
          bool rej = (k < 0.0f) | ((usB < (float)0.013) & (vB > usB));
          bool acc = false;
          if (!rej) {
            float s = xla_logf((vB * c.inv_alpha) / (c.aa / (usB * usB) + c.bb));
            acc = (s <= t_lookup(k, ttab));
          }
          if (!acc) {
            uint32_t qi = atomicAdd(&qn[0], 1u);
            if (qi < QCAP) qf[0][qi] = liB;
            else { float kk; uint32_t Lc = CAP;
              for (uint32_t t2 = 1; t2 < CAP; ++t2)
                if (trial(eB, t2, ssub, c, ttab, kk)) { Lc = t2 + 1u; break; }
              atomicMax(&shN, Lc); }
          }
        }
      }
    }
    // Wave-local dense flush (no barrier).
    uint32_t n = wcnt < WAQ_CAP ? wcnt : WAQ_CAP;
    uint32_t lane = threadIdx.x & 63u;
    for (uint32_t base = 0; base < n; base += 64u) {
      uint32_t i = base + lane;
      bool live = (i < n);
      uint16_t li = live ? wli[wid][i] : (uint16_t)0;
      float u = live ? wu[wid][i] : 0.1f;
      float v = live ? wv[wid][i] : 0.0f;
      float us = 0.5f - fabsf(u);
      float inner = c.twoa / us + c.bb;
      float k = floorf(__builtin_fmaf(inner, u, 500.43f));
      bool rej = (k < 0.0f) | ((us < (float)0.013) & (v > us));
      bool acc = false;
      if (live & !rej) {
        float s = xla_logf((v * c.inv_alpha) / (c.aa / (us * us) + c.bb));
        acc = (s <= t_lookup(k, ttab));
      }
      bool fail = live & !acc;
      uint32_t qi = wq_push(&qn[0], fail);
      if (fail) {
        if (__builtin_expect(qi < QCAP, 1)) qf[0][qi] = li;
        else {
          uint32_t e = blockBase + (li & 255u) + (uint32_t)(li >> 8) * TOTAL_THREADS;
          float kk; uint32_t Lc = CAP;
          for (uint32_t t2 = 1; t2 < CAP; ++t2)
            if (trial(e, t2, ssub, c, ttab, kk)) { Lc = t2 + 1u; break; }
          atomicMax(&shN, Lc);
        }
      }
    }
    wcnt = 0;
  }
  __syncthreads();
  // Block-wide level phases (levels 1..).
  int cur = 0;
  uint32_t localN = 1;
  for (uint32_t t = 1; t < CAP; ++t) {
    uint32_t n = qn[cur]; if (n > QCAP) n = QCAP;
    if (n == 0) break;
    localN = t + 1u;
    if (threadIdx.x == 0) qn[cur ^ 1] = 0;
    __syncthreads();
    for (uint32_t i = threadIdx.x; i < n; i += N_TPB) {
      uint16_t li = qf[cur][i];
      uint32_t e = blockBase + (li & 255u) + (uint32_t)(li >> 8) * TOTAL_THREADS;
      float kk;
      bool fail = !trial(e, t, ssub, c, ttab, kk);
      uint32_t qi = wq_push(&qn[cur ^ 1], fail);
      if (fail) {
        if (__builtin_expect(qi < QCAP, 1)) qf[cur ^ 1][qi] = li;
        else {
          uint32_t Lc = CAP;
          for (uint32_t t2 = t + 1; t2 < CAP; ++t2)
            if (trial(e, t2, ssub, c, ttab, kk)) { Lc = t2 + 1u; break; }
          atomicMax(&shN, Lc);
        }
      }
    }
    __syncthreads();
    cur ^= 1;
  }
  __syncthreads();
  if (threadIdx.x == 0) {
    uint32_t m = shN; if (localN > m) m = localN;
    atomicMax(nmax, m);
  }
}

// ---------------- Pass 2: last-accept scanning N-1 .. 0 ----------------
__global__ __launch_bounds__(N_TPB) void pn_pass2(const float* __restrict__ img,
                                                  float* __restrict__ out,
                                                  const uint32_t* __restrict__ nptr) {
  __shared__ uint32_t ssub[CAP][4];
  __shared__ float ttab[TAB_N];
  __shared__ uint16_t qf[2][QCAP];
  __shared__ uint32_t qn[2];
  __shared__ uint16_t wli[NWAVES][WAQ_CAP];
  __shared__ uint16_t wk[NWAVES][WAQ_CAP];
  __shared__ float wus[NWAVES][WAQ_CAP];
  __shared__ float wv[NWAVES][WAQ_CAP];
  uint32_t N = *nptr;
  if (N < 1u) N = 1u;
  if (N > CAP) N = CAP;
  if (threadIdx.x == 0) { qn[0] = 0; qn[1] = 0; }
  build_shared(N, ssub, ttab);
  PC c = make_pc();
  uint32_t blockBase = blockIdx.x * N_TPB;
  uint32_t top = N - 1u;
  uint32_t wid = threadIdx.x >> 6;
  uint32_t wcnt = 0;
  // Phase A: level top. accept1 -> write; reject -> block queue; accept2 -> wave-local.
  for (int jc = 0; jc < ELEMS_PER_THREAD; jc += CHUNK_J) {
    for (int j = jc; j < jc + CHUNK_J; j += 2) {
      uint32_t eA = blockBase + threadIdx.x + (uint32_t)j * TOTAL_THREADS;
      uint32_t eB = eA + TOTAL_THREADS;
      uint16_t liA = (uint16_t)(((uint32_t)j << 8) | threadIdx.x);
      uint16_t liB = (uint16_t)liA + (uint16_t)256;
      uint32_t ubA = pbits(ssub[top][0], ssub[top][1], eA);
      uint32_t vbA = pbits(ssub[top][2], ssub[top][3], eA);
      uint32_t ubB = pbits(ssub[top][0], ssub[top][1], eB);
      uint32_t vbB = pbits(ssub[top][2], ssub[top][3], eB);
      float uA = bits_to_u01(ubA) - 0.5f, vA = bits_to_u01(vbA);
      float uB = bits_to_u01(ubB) - 0.5f, vB = bits_to_u01(vbB);
      float usA = 0.5f - fabsf(uA), usB = 0.5f - fabsf(uB);
      float kA = floorf(__builtin_fmaf(c.twoa / usA + c.bb, uA, 500.43f));
      float kB = floorf(__builtin_fmaf(c.twoa / usB + c.bb, uB, 500.43f));
      bool a1A = (usA >= (float)0.07) & (vA <= c.v_r);
      bool a1B = (usB >= (float)0.07) & (vB <= c.v_r);
      bool rjA = (!a1A) & ((kA < 0.0f) | ((usA < (float)0.013) & (vA > usA)));
      bool rjB = (!a1B) & ((kB < 0.0f) | ((usB < (float)0.013) & (vB > usB)));
      bool n2A = (!a1A) & (!rjA);
      bool n2B = (!a1B) & (!rjB);
      if (a1A) out[eA] = img[eA] + kA;
      if (a1B) out[eB] = img[eB] + kB;
      uint32_t qiA = wq_push(&qn[0], rjA);
      if (rjA) {
        if (__builtin_expect(qiA < QCAP, 1)) qf[0][qiA] = liA;
        else { float kk, kf = -1.0f;
          for (int t2 = (int)top - 1; t2 >= 0; --t2)
            if (trial(eA, (uint32_t)t2, ssub, c, ttab, kk)) { kf = kk; break; }
          out[eA] = img[eA] + kf; }
      }
      uint32_t qiB = wq_push(&qn[0], rjB);
      if (rjB) {
        if (__builtin_expect(qiB < QCAP, 1)) qf[0][qiB] = liB;
        else { float kk, kf = -1.0f;
          for (int t2 = (int)top - 1; t2 >= 0; --t2)
            if (trial(eB, (uint32_t)t2, ssub, c, ttab, kk)) { kf = kk; break; }
          out[eB] = img[eB] + kf; }
      }
      uint32_t oA = wl_push(wcnt, n2A);
      if (n2A) {
        if (__builtin_expect(oA < WAQ_CAP, 1)) {
          wli[wid][oA]=liA; wk[wid][oA]=(uint16_t)(int)kA; wus[wid][oA]=usA; wv[wid][oA]=vA;
        } else {
          float s = xla_logf((vA * c.inv_alpha) / (c.aa / (usA * usA) + c.bb));
          if (s <= t_lookup(kA, ttab)) out[eA] = img[eA] + kA;
          else { uint32_t qi2 = atomicAdd(&qn[0], 1u);
            if (qi2 < QCAP) qf[0][qi2] = liA;
            else { float kk, kf = -1.0f;
              for (int t2 = (int)top - 1; t2 >= 0; --t2)
                if (trial(eA, (uint32_t)t2, ssub, c, ttab, kk)) { kf = kk; break; }
              out[eA] = img[eA] + kf; } }
        }
      }
      uint32_t oB = wl_push(wcnt, n2B);
      if (n2B) {
        if (__builtin_expect(oB < WAQ_CAP, 1)) {
          wli[wid][oB]=liB; wk[wid][oB]=(uint16_t)(int)kB; wus[wid][oB]=usB; wv[wid][oB]=vB;
        } else {
          float s = xla_logf((vB * c.inv_alpha) / (c.aa / (usB * usB) + c.bb));
          if (s <= t_lookup(kB, ttab)) out[eB] = img[eB] + kB;
          else { uint32_t qi2 = atomicAdd(&qn[0], 1u);
            if (qi2 < QCAP) qf[0][qi2] = liB;
            else { float kk, kf = -1.0f;
              for (int t2 = (int)top - 1; t2 >= 0; --t2)
                if (trial(eB, (uint32_t)t2, ssub, c, ttab, kk)) { kf = kk; break; }
              out[eB] = img[eB] + kf; } }
        }
      }
    }
    // Wave-local accept2 flush (no barrier).
    uint32_t n = wcnt < WAQ_CAP ? wcnt : WAQ_CAP;
    uint32_t lane = threadIdx.x & 63u;
    for (uint32_t base = 0; base < n; base += 64u) {
      uint32_t i = base + lane;
      bool live = (i < n);
      uint16_t li = live ? wli[wid][i] : (uint16_t)0;
      float k  = live ? (float)(int)wk[wid][i] : 500.0f;
      float us = live ? wus[wid][i] : 0.1f;
      float v  = live ? wv[wid][i] : 0.0f;
      uint32_t e = blockBase + (li & 255u) + (uint32_t)(li >> 8) * TOTAL_THREADS;
      float s = xla_logf((v * c.inv_alpha) / (c.aa / (us * us) + c.bb));
      bool acc = live & (s <= t_lookup(k, ttab));
      if (acc) out[e] = img[e] + k;
      bool fail = live & !acc;
      uint32_t qi = wq_push(&qn[0], fail);
      if (fail) {
        if (__builtin_expect(qi < QCAP, 1)) qf[0][qi] = li;
        else { float kk, kf = -1.0f;
          for (int t2 = (int)top - 1; t2 >= 0; --t2)
            if (trial(e, (uint32_t)t2, ssub, c, ttab, kk)) { kf = kk; break; }
          out[e] = img[e] + kf; }
      }
    }
    wcnt = 0;
  }
  __syncthreads();
  // Block-wide level phases: top-1 .. 0.
  int cur = 0;
  for (int t = (int)top - 1; t >= 0; --t) {
    uint32_t n = qn[cur]; if (n > QCAP) n = QCAP;
    if (n == 0) break;
    if (threadIdx.x == 0) qn[cur ^ 1] = 0;
    __syncthreads();
    for (uint32_t i = threadIdx.x; i < n; i += N_TPB) {
      uint16_t li = qf[cur][i];
      uint32_t e = blockBase + (li & 255u) + (uint32_t)(li >> 8) * TOTAL_THREADS;
      float kk;
      bool acc = trial(e, (uint32_t)t, ssub, c, ttab, kk);
      if (acc) out[e] = img[e] + kk;
      uint32_t qi = wq_push(&qn[cur ^ 1], !acc);
      if (!acc) {
        if (__builtin_expect(qi < QCAP, 1)) qf[cur ^ 1][qi] = li;
        else { float kk2, kf = -1.0f;
          for (int t2 = t - 1; t2 >= 0; --t2)
            if (trial(e, (uint32_t)t2, ssub, c, ttab, kk2)) { kf = kk2; break; }
          out[e] = img[e] + kf; }
      }
    }
    __syncthreads();
    cur ^= 1;
  }
  // Drain: rejected at all levels -> k = -1 (JAX k_init).
  uint32_t n = qn[cur]; if (n > QCAP) n = QCAP;
  for (uint32_t i = threadIdx.x; i < n; i += N_TPB) {
    uint16_t li = qf[cur][i];
    uint32_t e = blockBase + (li & 255u) + (uint32_t)(li >> 8) * TOTAL_THREADS;
    out[e] = img[e] - 1.0f;
  }
}

extern "C" void kernel_launch(void* const* d_in, const int* in_sizes, int n_in,
                              void* d_out, int out_size, void* d_ws, size_t ws_size,
                              hipStream_t stream) {
  (void)in_sizes; (void)n_in; (void)out_size; (void)ws_size;
  const float* img = (const float*)d_in[0];
  float* out = (float*)d_out;
  uint32_t* nmax = (uint32_t*)d_ws;
  pn_init<<<1, 1, 0, stream>>>(nmax);
  pn_pass1<<<N_BLOCKS, N_TPB, 0, stream>>>(nmax);
  pn_pass2<<<N_BLOCKS, N_TPB, 0, stream>>>(img, out, nmax);
}